// Round 7
// baseline (161.579 us; speedup 1.0000x reference)
//
#include <hip/hip_runtime.h>
#include <hip/hip_bf16.h>
#include <math.h>

#define C_IN  64
#define HID   128
#define C_OUT 64
#define K1_NODES 64
#define EA_G  6144

typedef __attribute__((ext_vector_type(8))) short s16x8;   // 8 bf16 (4 VGPR)
typedef __attribute__((ext_vector_type(4))) float f32x4;   // MFMA acc
typedef __attribute__((ext_vector_type(2))) float f32x2;   // packed-fp32 pair

typedef const __attribute__((address_space(1))) unsigned g1u32;
typedef __attribute__((address_space(3))) unsigned l3u32;

// ---------------------------------------------------------------------------
// Fast GELU (tanh form), PACKED 2-wide. Bit-identical math to prior rounds.
// ---------------------------------------------------------------------------
__device__ __forceinline__ f32x2 gelu2(f32x2 x) {
    f32x2 t  = x * x;                                   // pk_mul
    f32x2 p  = t * 0.10294455f + 2.30211462f;           // pk_fma
    f32x2 xp = x * p;                                   // pk_mul
    f32x2 E;
    E.x = __builtin_amdgcn_exp2f(xp.x);                 // trans
    E.y = __builtin_amdgcn_exp2f(xp.y);                 // trans
    f32x2 Ep = E + 1.0f;                                // pk_add
    f32x2 r;
    r.x = __builtin_amdgcn_rcpf(Ep.x);                  // trans
    r.y = __builtin_amdgcn_rcpf(Ep.y);                  // trans
    return x - x * r;                                   // pk_fma
}

__device__ __forceinline__ float4 fma4(float s, float4 w, float4 acc) {
    acc.x = fmaf(s, w.x, acc.x); acc.y = fmaf(s, w.y, acc.y);
    acc.z = fmaf(s, w.z, acc.z); acc.w = fmaf(s, w.w, acc.w);
    return acc;
}

__device__ __forceinline__ unsigned pk_bf16(float lo, float hi) {
    union { __hip_bfloat162 v; unsigned u; } cv;
    cv.v = __float22bfloat162_rn(make_float2(lo, hi));
    return cv.u;
}
// unpack dword of 2x bf16 -> f32x2 (consecutive VGPRs -> pk-friendly)
__device__ __forceinline__ f32x2 unpk2(unsigned p) {
    union { unsigned u; float f; } lo, hi;
    lo.u = p << 16; hi.u = p & 0xffff0000u;
    f32x2 v; v.x = lo.f; v.y = hi.f; return v;
}

// ---------------------------------------------------------------------------
// Kernel 1: per-node factored first linear ([50000x64] @ [64x256] GEMM).
//   A16[n][h] = bf16( X[n][:] . W1[0:64,h] )       (gathered per-edge)
//   B  [n][h] =       X[n][:] . W1[64:128,h] + b1  (read per-row, f32)
// Block 0 additionally transposes W2 -> W2T[c][k] bf16 for the MFMA kernel.
// Also precomputes the edge-balanced block->row partition for edge_agg.
// ---------------------------------------------------------------------------
__global__ __launch_bounds__(512, 2) void precompute_ab(
    const float* __restrict__ X, const float* __restrict__ W1,
    const float* __restrict__ b1, const float* __restrict__ W2,
    const int* __restrict__ rs,
    unsigned* __restrict__ A16, float* __restrict__ B,
    unsigned short* __restrict__ W2T, int* __restrict__ bsplit,
    int N, int E, int G)
{
    __shared__ float W1s[2 * C_IN * HID];     // 64 KiB
    __shared__ float xs[K1_NODES * C_IN];     // 16 KiB
    int tid = threadIdx.x;

    for (int i = tid; i < (2 * C_IN * HID) / 4; i += 512)
        ((float4*)W1s)[i] = ((const float4*)W1)[i];

    int base = blockIdx.x * K1_NODES;
    int nLoc = min(K1_NODES, N - base);
    for (int i = tid; i < nLoc * (C_IN / 4); i += 512)
        ((float4*)xs)[i] = ((const float4*)(X + (size_t)base * C_IN))[i];

    if (blockIdx.x == 0) {                     // one-time W2 -> bf16 k-major
        for (int i = tid; i < C_OUT * HID; i += 512) {
            int c = i >> 7, k = i & (HID - 1);
            W2T[i] = (unsigned short)pk_bf16(W2[k * C_OUT + c], 0.f);
        }
    }

    // ---- block->row partition for edge_agg (lane-parallel binary search) ----
    {
        int gi = blockIdx.x * 512 + tid;
        if (gi <= G) {
            int t = (int)(((long long)E * gi) / G);
            int lo = 0, hi = N;
            while (lo < hi) { int mm = (lo + hi) >> 1; if (rs[mm] < t) lo = mm + 1; else hi = mm; }
            bsplit[gi] = lo;
        }
    }

    __syncthreads();

    int quad = (tid & 31) * 4;    // h-quad 0,4,...,124
    int slot = tid >> 5;          // 0..15, owns nodes 4*slot .. 4*slot+3
    int s0   = slot * 4;
    if (s0 >= nLoc) return;

    float4 a0 = {}, a1 = {}, a2 = {}, a3 = {};
    float4 b0 = {}, b1r = {}, b2r = {}, b3 = {};

    const float* xr0 = xs + (s0 + 0) * C_IN;
    const float* xr1 = xs + (s0 + 1) * C_IN;
    const float* xr2 = xs + (s0 + 2) * C_IN;
    const float* xr3 = xs + (s0 + 3) * C_IN;

#define K1STEP(c, CMP)                                                      \
    do {                                                                    \
        float4 wa = *(const float4*)&W1s[(c) * HID + quad];                 \
        float4 wb = *(const float4*)&W1s[((c) + C_IN) * HID + quad];        \
        a0 = fma4(xv0.CMP, wa, a0); b0  = fma4(xv0.CMP, wb, b0);            \
        a1 = fma4(xv1.CMP, wa, a1); b1r = fma4(xv1.CMP, wb, b1r);           \
        a2 = fma4(xv2.CMP, wa, a2); b2r = fma4(xv2.CMP, wb, b2r);           \
        a3 = fma4(xv3.CMP, wa, a3); b3  = fma4(xv3.CMP, wb, b3);            \
    } while (0)

#pragma unroll 1
    for (int c4 = 0; c4 < C_IN; c4 += 4) {
        float4 xv0 = *(const float4*)&xr0[c4];
        float4 xv1 = *(const float4*)&xr1[c4];
        float4 xv2 = *(const float4*)&xr2[c4];
        float4 xv3 = *(const float4*)&xr3[c4];
        K1STEP(c4 + 0, x);
        K1STEP(c4 + 1, y);
        K1STEP(c4 + 2, z);
        K1STEP(c4 + 3, w);
    }
#undef K1STEP

    float4 bb = *(const float4*)(b1 + quad);
    b0.x += bb.x;  b0.y += bb.y;  b0.z += bb.z;  b0.w += bb.w;
    b1r.x += bb.x; b1r.y += bb.y; b1r.z += bb.z; b1r.w += bb.w;
    b2r.x += bb.x; b2r.y += bb.y; b2r.z += bb.z; b2r.w += bb.w;
    b3.x += bb.x;  b3.y += bb.y;  b3.z += bb.z;  b3.w += bb.w;

    int adw = (base + s0) * (HID / 2) + (quad >> 1);
    size_t boff = (size_t)(base + s0) * HID + quad;
    if (s0 + 0 < nLoc) {
        uint2 u = { pk_bf16(a0.x, a0.y), pk_bf16(a0.z, a0.w) };
        *(uint2*)(A16 + adw) = u;              *(float4*)(B + boff) = b0;
    }
    if (s0 + 1 < nLoc) {
        uint2 u = { pk_bf16(a1.x, a1.y), pk_bf16(a1.z, a1.w) };
        *(uint2*)(A16 + adw + HID / 2) = u;    *(float4*)(B + boff + HID) = b1r;
    }
    if (s0 + 2 < nLoc) {
        uint2 u = { pk_bf16(a2.x, a2.y), pk_bf16(a2.z, a2.w) };
        *(uint2*)(A16 + adw + HID) = u;        *(float4*)(B + boff + 2 * HID) = b2r;
    }
    if (s0 + 3 < nLoc) {
        uint2 u = { pk_bf16(a3.x, a3.y), pk_bf16(a3.z, a3.w) };
        *(uint2*)(A16 + adw + 3 * (HID / 2)) = u; *(float4*)(B + boff + 3 * HID) = b3;
    }
}

// ---------------------------------------------------------------------------
// Kernel 2: LDS-staged gather pipeline (global_load_lds, per-lane gather src).
//   * 1 wave/block; 2 LDS slots x 32 edges x 256B = 16 KB; NO barriers.
//   * stage: 8 x global_load_lds(16B/lane) per chunk -> 4 random rows / instr,
//     zero VGPR cost; double-buffered one chunk ahead.
//   * constant vmcnt schedule per iter: [store 1][meta 2][stage 8] with
//     compile-time waits vmcnt(11)/vmcnt(9); compiler fences pin issue order.
//   * consume: ds_read_b64 per 2 edges (conflict-free), same gelu2 math and
//     accumulation order as R2 -> bit-identical output.
// ---------------------------------------------------------------------------
#define WAITVM(N) do { asm volatile("s_waitcnt vmcnt(" #N ")" ::: "memory");  \
                       __builtin_amdgcn_sched_barrier(0); } while (0)
#define VMFENCE() asm volatile("" ::: "memory")

#define EA_ADV() do {                                                         \
    if (srow >= r1) { dn_row = -1; dn_pos = 0; dn_len = 0; dn_cnt = 1; dn_first = 0; } \
    else {                                                                    \
        dn_row = srow; dn_pos = spos; dn_cnt = e0 - sS;                       \
        dn_first = (spos == sS) ? 1 : 0;                                      \
        int _rem = e0 - spos; dn_len = _rem < 32 ? _rem : 32;                 \
        spos += dn_len;                                                       \
        if (spos >= e0) {                                                     \
            ++srow; sS = e0; e0 = e1; spos = sS;                              \
            int _ni = srow + 2; _ni = _ni < N ? _ni : N;                      \
            e1 = rs[__builtin_amdgcn_readfirstlane(_ni)];                     \
        }                                                                     \
    } } while (0)

#define EA_META(DROW, DPOS, DLEN, IDXR, BBR) do {                             \
    int _cl = (DLEN) > 0 ? (DLEN) - 1 : 0;                                    \
    int _li = (DPOS) + (lane < _cl ? lane : _cl);                             \
    _li = _li < E - 1 ? _li : E - 1; _li = _li > 0 ? _li : 0;                 \
    IDXR = nbr[_li];                                                          \
    int _br = (DROW) >= 0 ? (DROW) : 0;                                       \
    BBR = *(const float4*)(B + ((size_t)_br << 7) + (l5 << 2));               \
} while (0)

#define EA_STAGE8(SLOTP, LEN, IDXR) do {                                      \
    int _cl = (LEN) > 0 ? (LEN) - 1 : 0;                                      \
    char* _sp = (SLOTP);                                                      \
    _Pragma("unroll")                                                         \
    for (int _g = 0; _g < 8; ++_g) {                                          \
        int _sh = (_g << 2) + (lane >> 4); _sh = _sh < _cl ? _sh : _cl;       \
        int _ie = __shfl((IDXR), _sh);                                        \
        const char* _gp = A8 + (((size_t)(unsigned)_ie) << 8) + ((lane & 15) << 4); \
        __builtin_amdgcn_global_load_lds((g1u32*)_gp,                         \
                                         (l3u32*)(_sp + (_g << 10)), 16, 0, 0); \
    } } while (0)

#define EA_LDE(SLOT, G, T) (*(const uint2*)((SLOT) + ((((G)<<3)+((T)<<1)+half)<<8) + (l5<<3)))

#define EA_PAIR(P) do {                                                       \
    acc01 += gelu2(unpk2(P.x) + bb01);                                        \
    acc23 += gelu2(unpk2(P.y) + bb23); } while (0)

#define EA_PAIRM(P, EB) do {                                                  \
    float _mk = ((EB) + half < m) ? 1.f : 0.f;                                \
    acc01 += gelu2(unpk2(P.x) + bb01) * _mk;                                  \
    acc23 += gelu2(unpk2(P.y) + bb23) * _mk; } while (0)

#define EA_GRP(SLOT, G) do {                                                  \
    if (((G) << 3) < m) {                                                     \
        uint2 _P0 = EA_LDE(SLOT, G, 0), _P1 = EA_LDE(SLOT, G, 1);             \
        uint2 _P2 = EA_LDE(SLOT, G, 2), _P3 = EA_LDE(SLOT, G, 3);             \
        if ((((G) + 1) << 3) <= m) {                                          \
            EA_PAIR(_P0); EA_PAIR(_P1); EA_PAIR(_P2); EA_PAIR(_P3);           \
        } else { int _eb = (G) << 3;                                          \
            EA_PAIRM(_P0, _eb);                                               \
            if (_eb + 2 < m) EA_PAIRM(_P1, _eb + 2);                          \
            if (_eb + 4 < m) EA_PAIRM(_P2, _eb + 4);                          \
            if (_eb + 6 < m) EA_PAIRM(_P3, _eb + 6);                          \
        }                                                                     \
    } } while (0)

__global__ __launch_bounds__(64, 2) void edge_agg(
    const unsigned* __restrict__ A16, const float* __restrict__ B,
    const int* __restrict__ nbr, const int* __restrict__ rs,
    const int* __restrict__ bsplit,
    unsigned* __restrict__ Hout, unsigned* __restrict__ dump,
    int N, int E, int G)
{
    __shared__ __align__(1024) char lds0[8192];
    __shared__ __align__(1024) char lds1[8192];

    int lane = threadIdx.x;                 // 64-thr block = 1 wave
    int half = lane >> 5, l5 = lane & 31;
    const char* A8 = (const char*)A16;
    int b = blockIdx.x;

    int r0 = bsplit[b];
    int r1 = (b == G - 1) ? N : bsplit[b + 1];
    if (r0 >= r1) return;

    // staging cursor (wave-uniform)
    int srow = r0;
    int sS = rs[r0];
    int e0 = rs[r0 + 1];
    int ni0 = r0 + 2; ni0 = ni0 < N ? ni0 : N;
    int e1 = rs[ni0];
    int spos = sS;

    // descriptors: d0 = consume-now, d1, d2 = staged-ahead
    int dn_row, dn_pos, dn_len, dn_cnt, dn_first;
    EA_ADV();
    int d0_row = dn_row, d0_pos = dn_pos, d0_len = dn_len, d0_cnt = dn_cnt, d0_first = dn_first;
    EA_ADV();
    int d1_row = dn_row, d1_pos = dn_pos, d1_len = dn_len, d1_cnt = dn_cnt, d1_first = dn_first;
    EA_ADV();
    int d2_row = dn_row, d2_pos = dn_pos, d2_len = dn_len, d2_cnt = dn_cnt, d2_first = dn_first;

    int idxT0, idxT1, idxS, idxA;
    float4 bb0, bb1, bb2;

    // prologue: build the exact steady-state vmcnt stream
    EA_META(d0_row, d0_pos, d0_len, idxT0, bb0);     // 2 vmem
    EA_META(d1_row, d1_pos, d1_len, idxT1, bb1);     // 2 vmem
    WAITVM(0);
    EA_STAGE8(lds0, d0_len, idxT0);                  // 8 vmem
    VMFENCE();
    if (half == 0) { uint2 z = {0u, 0u}; ((uint2*)dump)[l5] = z; }  // 1 vmem
    VMFENCE();
    EA_META(d2_row, d2_pos, d2_len, idxS, bb2);      // 2 vmem
    VMFENCE();
    EA_STAGE8(lds1, d1_len, idxT1);                  // 8 vmem
    // outstanding (oldest->newest): STAGE(d0)8, store1, META(d2)2, STAGE(d1)8 = 19

    char* slotC = lds0;
    char* slotS = lds1;
    f32x2 acc01 = {0.f, 0.f}, acc23 = {0.f, 0.f};

    for (;;) {
        if (d0_row < 0) break;

        WAITVM(11);                                  // chunk d0 fully staged
        // ---- consume d0 from slotC ----
        if (d0_first) { acc01.x = 0.f; acc01.y = 0.f; acc23.x = 0.f; acc23.y = 0.f; }
        f32x2 bb01, bb23;
        bb01.x = bb0.x; bb01.y = bb0.y; bb23.x = bb0.z; bb23.y = bb0.w;
        int m = d0_len;
        EA_GRP(slotC, 0);
        EA_GRP(slotC, 1);
        EA_GRP(slotC, 2);
        EA_GRP(slotC, 3);

        // reduce (copies; acc itself carries across chunks of long rows)
        f32x2 r01 = acc01, r23 = acc23;
        r01.x += __shfl_xor(r01.x, 32);
        r01.y += __shfl_xor(r01.y, 32);
        r23.x += __shfl_xor(r23.x, 32);
        r23.y += __shfl_xor(r23.y, 32);
        VMFENCE();
        if (half == 0) {                             // 1 vmem (every iteration)
            float sc = (d0_cnt > 0) ? 1.f / (float)d0_cnt : 0.f;
            uint2 o = { pk_bf16(r01.x * sc, r01.y * sc),
                        pk_bf16(r23.x * sc, r23.y * sc) };
            ((uint2*)(Hout + ((size_t)d0_row << 6)))[l5] = o;
        }
        VMFENCE();

        WAITVM(9);                                   // META(d2): idxS + bb2 landed
        EA_ADV();                                    // descriptor for c+3
        idxA = idxS;
        bb0 = bb1; bb1 = bb2;
        EA_META(dn_row, dn_pos, dn_len, idxS, bb2);  // 2 vmem
        VMFENCE();
        EA_STAGE8(slotC, d2_len, idxA);              // 8 vmem (into just-freed slot)

        // rotate descriptors + slots
        d0_row = d1_row; d0_pos = d1_pos; d0_len = d1_len; d0_cnt = d1_cnt; d0_first = d1_first;
        d1_row = d2_row; d1_pos = d2_pos; d1_len = d2_len; d1_cnt = d2_cnt; d1_first = d2_first;
        d2_row = dn_row; d2_pos = dn_pos; d2_len = dn_len; d2_cnt = dn_cnt; d2_first = dn_first;
        char* tmp = slotC; slotC = slotS; slotS = tmp;
    }
}

#undef EA_ADV
#undef EA_META
#undef EA_STAGE8
#undef EA_LDE
#undef EA_PAIR
#undef EA_PAIRM
#undef EA_GRP

// ---------------------------------------------------------------------------
// Kernel 3: out = Hbar @ W2 + b2 via MFMA (bf16 in, f32 out). Unchanged.
// ---------------------------------------------------------------------------
__global__ __launch_bounds__(256) void h_w2_mfma(
    const unsigned short* __restrict__ H, const unsigned short* __restrict__ W2T,
    const float* __restrict__ b2, const int* __restrict__ rs,
    float* __restrict__ out, int N)
{
    int wave = threadIdx.x >> 6, lane = threadIdx.x & 63;
    int base = (blockIdx.x * 4 + wave) * 16;
    if (base >= N) return;

    int r16 = lane & 15;
    int kg  = lane >> 4;

    const unsigned short* hrow = H + (size_t)(base + r16) * HID + kg * 8;
    const unsigned short* wc0  = W2T + (size_t)(0 * 16 + r16) * HID + kg * 8;
    const unsigned short* wc1  = W2T + (size_t)(1 * 16 + r16) * HID + kg * 8;
    const unsigned short* wc2  = W2T + (size_t)(2 * 16 + r16) * HID + kg * 8;
    const unsigned short* wc3  = W2T + (size_t)(3 * 16 + r16) * HID + kg * 8;

    f32x4 acc0 = {0.f, 0.f, 0.f, 0.f};
    f32x4 acc1 = acc0, acc2 = acc0, acc3 = acc0;

#pragma unroll
    for (int kk = 0; kk < 4; ++kk) {
        s16x8 a  = *(const s16x8*)(hrow + kk * 32);
        s16x8 f0 = *(const s16x8*)(wc0 + kk * 32);
        s16x8 f1 = *(const s16x8*)(wc1 + kk * 32);
        s16x8 f2 = *(const s16x8*)(wc2 + kk * 32);
        s16x8 f3 = *(const s16x8*)(wc3 + kk * 32);
        acc0 = __builtin_amdgcn_mfma_f32_16x16x32_bf16(a, f0, acc0, 0, 0, 0);
        acc1 = __builtin_amdgcn_mfma_f32_16x16x32_bf16(a, f1, acc1, 0, 0, 0);
        acc2 = __builtin_amdgcn_mfma_f32_16x16x32_bf16(a, f2, acc2, 0, 0, 0);
        acc3 = __builtin_amdgcn_mfma_f32_16x16x32_bf16(a, f3, acc3, 0, 0, 0);
    }

    float bia0 = b2[r16], bia1 = b2[16 + r16], bia2 = b2[32 + r16], bia3 = b2[48 + r16];

#pragma unroll
    for (int r = 0; r < 4; ++r) {
        int rowi = base + kg * 4 + r;
        if (rowi < N) {
            float mmk = (rs[rowi + 1] > rs[rowi]) ? 1.f : 0.f;
            float* o = out + (size_t)rowi * C_OUT;
            o[r16]      = mmk * (acc0[r] + bia0);
            o[16 + r16] = mmk * (acc1[r] + bia1);
            o[32 + r16] = mmk * (acc2[r] + bia2);
            o[48 + r16] = mmk * (acc3[r] + bia3);
        }
    }
}

// ---------------------------------------------------------------------------
extern "C" void kernel_launch(void* const* d_in, const int* in_sizes, int n_in,
                              void* d_out, int out_size, void* d_ws, size_t ws_size,
                              hipStream_t stream) {
    const float* X  = (const float*)d_in[0];
    const float* W1 = (const float*)d_in[1];
    const float* b1 = (const float*)d_in[2];
    const float* W2 = (const float*)d_in[3];
    const float* b2 = (const float*)d_in[4];
    const int*   nbr = (const int*)d_in[5];
    const int*   rs  = (const int*)d_in[6];
    float* outp = (float*)d_out;

    int N = in_sizes[6] - 1;                  // row_splits has N+1 entries
    int E = in_sizes[5];                      // total edges

    int G = EA_G;

    // workspace layout (~51.3 MB):
    unsigned*       A16  = (unsigned*)d_ws;                          // N*64 dw
    float*          Bbuf = (float*)(A16 + (size_t)N * (HID / 2));    // N*128 f32
    unsigned*       Hout = (unsigned*)(Bbuf + (size_t)N * HID);      // N*64 dw
    unsigned short* W2T  = (unsigned short*)(Hout + (size_t)N * (HID / 2)); // 8192
    int*            bsplit = (int*)(W2T + C_OUT * HID);              // G+1 ints
    unsigned*       dump = (unsigned*)(bsplit + (G + 2));            // 64 dw scratch

    int g1 = (N + K1_NODES - 1) / K1_NODES;
    hipLaunchKernelGGL(precompute_ab, dim3(g1), dim3(512), 0, stream,
                       X, W1, b1, W2, rs, A16, Bbuf, W2T, bsplit, N, E, G);

    hipLaunchKernelGGL(edge_agg, dim3(G), dim3(64), 0, stream,
                       A16, Bbuf, nbr, rs, bsplit, Hout, dump, N, E, G);

    int stripes = (N + 15) / 16;
    int g3 = (stripes + 3) / 4;
    hipLaunchKernelGGL(h_w2_mfma, dim3(g3), dim3(256), 0, stream,
                       (const unsigned short*)Hout, W2T, b2, rs, outp, N);
}